// Round 1
// baseline (1038.698 us; speedup 1.0000x reference)
//
#include <hip/hip_runtime.h>

// Linear attention (elu+1 feature map), B=4 S=4096 D=2048 H=16 dk=128.
// Everything in bf16 MFMA with fp32 accumulate; the attention-ratio structure
// attenuates bf16 rounding far below the 1.17e-3 absmax threshold.

#define D_MODEL 2048
#define SEQ     4096
#define BATCH   4
#define HEADS   16
#define DKH     128
#define M_TOK   16384   // BATCH*SEQ
#define NBH     64      // BATCH*HEADS

using frag8 = __attribute__((ext_vector_type(8))) short;   // 8 bf16 (4 VGPRs)
using f32x4 = __attribute__((ext_vector_type(4))) float;   // 4 fp32 acc

__device__ __forceinline__ unsigned short f2bf(float f) {
  unsigned u = __float_as_uint(f);
  u = u + 0x7fffu + ((u >> 16) & 1u);   // round-to-nearest-even
  return (unsigned short)(u >> 16);
}
__device__ __forceinline__ float bf2f(unsigned short h) {
  return __uint_as_float(((unsigned)h) << 16);
}

// ---- fp32 -> bf16 convert (vectorized) --------------------------------------
__global__ __launch_bounds__(256) void convert_f2bf_kernel(
    const float* __restrict__ in, unsigned short* __restrict__ out, int n4) {
  int i = blockIdx.x * 256 + threadIdx.x;
  if (i < n4) {
    float4 v = reinterpret_cast<const float4*>(in)[i];
    ushort4 o;
    o.x = f2bf(v.x); o.y = f2bf(v.y); o.z = f2bf(v.z); o.w = f2bf(v.w);
    reinterpret_cast<ushort4*>(out)[i] = o;
  }
}

// ---- shared GEMM core: C[128x128] += A(128xK) * B(128xK)^T, bf16, NT -------
// 256 threads = 4 waves in 2x2; per-wave 64x64 = 4x4 fragments of 16x16x32.
__device__ __forceinline__ void stage_tile(const unsigned short* __restrict__ G,
                                           long ld, unsigned short* __restrict__ L) {
  int t = threadIdx.x;
#pragma unroll
  for (int r = 0; r < 4; ++r) {
    int e = (r * 256 + t) * 8;       // element index within 128x64 tile
    int row = e >> 6, col = e & 63;
    *reinterpret_cast<uint4*>(L + row * 64 + col) =
        *reinterpret_cast<const uint4*>(G + (long)row * ld + col);
  }
}

__device__ __forceinline__ void gemm_mainloop(const unsigned short* __restrict__ A, long lda,
                                              const unsigned short* __restrict__ B, long ldb,
                                              int K, unsigned short* lA, unsigned short* lB,
                                              f32x4 acc[4][4]) {
  const int lane = threadIdx.x & 63;
  const int wid  = threadIdx.x >> 6;
  const int wr = wid >> 1, wc = wid & 1;
  const int lr = lane & 15, lh = lane >> 4;
  for (int k0 = 0; k0 < K; k0 += 64) {
    stage_tile(A + k0, lda, lA);
    stage_tile(B + k0, ldb, lB);
    __syncthreads();
#pragma unroll
    for (int kk = 0; kk < 64; kk += 32) {
      frag8 av[4], bv[4];
#pragma unroll
      for (int m = 0; m < 4; ++m)
        av[m] = *reinterpret_cast<const frag8*>(lA + (wr * 64 + m * 16 + lr) * 64 + kk + lh * 8);
#pragma unroll
      for (int n = 0; n < 4; ++n)
        bv[n] = *reinterpret_cast<const frag8*>(lB + (wc * 64 + n * 16 + lr) * 64 + kk + lh * 8);
#pragma unroll
      for (int m = 0; m < 4; ++m)
#pragma unroll
        for (int n = 0; n < 4; ++n)
          acc[m][n] = __builtin_amdgcn_mfma_f32_16x16x32_bf16(av[m], bv[n], acc[m][n], 0, 0, 0);
    }
    __syncthreads();
  }
}

#define ACC_INIT(acc)                                   \
  _Pragma("unroll") for (int m_ = 0; m_ < 4; ++m_)      \
  _Pragma("unroll") for (int n_ = 0; n_ < 4; ++n_)      \
      acc[m_][n_] = (f32x4){0.f, 0.f, 0.f, 0.f};

// MODE: 0 = elu(v+bias[col])+1 -> bf16   (Q projection)
//       1 = elu(v+bias[row])+1 -> bf16   (K^T projection, bias is per-feature=row)
//       2 = v+bias[row]        -> bf16   (V^T projection)
//       3 = v+bias[col]        -> f32    (final output projection)
template <int MODE>
__global__ __launch_bounds__(256) void gemm_nt_kernel(
    const unsigned short* __restrict__ A, long lda,
    const unsigned short* __restrict__ Bm, long ldb,
    void* __restrict__ Cv, long ldc,
    const float* __restrict__ bias, int K) {
  __shared__ unsigned short lA[128 * 64], lB[128 * 64];
  const long m0 = (long)blockIdx.y * 128, n0 = (long)blockIdx.x * 128;
  f32x4 acc[4][4];
  ACC_INIT(acc);
  gemm_mainloop(A + m0 * lda, lda, Bm + n0 * ldb, ldb, K, lA, lB, acc);
  const int lane = threadIdx.x & 63, wid = threadIdx.x >> 6;
  const int wr = wid >> 1, wc = wid & 1, lr = lane & 15, lh = lane >> 4;
#pragma unroll
  for (int m = 0; m < 4; ++m)
#pragma unroll
    for (int n = 0; n < 4; ++n)
#pragma unroll
      for (int r = 0; r < 4; ++r) {
        long row = m0 + wr * 64 + m * 16 + lh * 4 + r;
        long col = n0 + wc * 64 + n * 16 + lr;
        float v = acc[m][n][r];
        if (MODE == 0) {
          v += bias[col]; v = v > 0.f ? v + 1.f : __expf(v);
          ((unsigned short*)Cv)[row * ldc + col] = f2bf(v);
        } else if (MODE == 1) {
          v += bias[row]; v = v > 0.f ? v + 1.f : __expf(v);
          ((unsigned short*)Cv)[row * ldc + col] = f2bf(v);
        } else if (MODE == 2) {
          v += bias[row];
          ((unsigned short*)Cv)[row * ldc + col] = f2bf(v);
        } else {
          v += bias[col];
          ((float*)Cv)[row * ldc + col] = v;
        }
      }
}

// ---- KV^T partials: per (bh, chunk) C[e,d] = sum_t V[t,e]K[t,d] over 512 t --
__global__ __launch_bounds__(256) void kvt_partial_kernel(
    const unsigned short* __restrict__ VT, const unsigned short* __restrict__ KT,
    float* __restrict__ part) {
  __shared__ unsigned short lA[128 * 64], lB[128 * 64];
  const int z = blockIdx.x;            // 0..511 = bh*8 + chunk
  const int bh = z >> 3, c = z & 7;
  const int b = bh >> 4, h = bh & 15;
  const long tOff = (long)b * SEQ + (long)c * 512;
  const unsigned short* A  = VT + (long)(h * DKH) * M_TOK + tOff;
  const unsigned short* Bm = KT + (long)(h * DKH) * M_TOK + tOff;
  f32x4 acc[4][4];
  ACC_INIT(acc);
  gemm_mainloop(A, M_TOK, Bm, M_TOK, 512, lA, lB, acc);
  const int lane = threadIdx.x & 63, wid = threadIdx.x >> 6;
  const int wr = wid >> 1, wc = wid & 1, lr = lane & 15, lh = lane >> 4;
  float* out = part + (long)z * (DKH * DKH);
#pragma unroll
  for (int m = 0; m < 4; ++m)
#pragma unroll
    for (int n = 0; n < 4; ++n)
#pragma unroll
      for (int r = 0; r < 4; ++r) {
        int row = wr * 64 + m * 16 + lh * 4 + r;   // e
        int col = wc * 64 + n * 16 + lr;           // d
        out[row * DKH + col] = acc[m][n][r];
      }
}

__global__ __launch_bounds__(256) void reduce_kvt_kernel(
    const float* __restrict__ part, unsigned short* __restrict__ kvt) {
  int i = blockIdx.x * 256 + threadIdx.x;          // over 64*16384
  if (i < NBH * DKH * DKH) {
    int bh = i >> 14, j = i & 16383;
    float s = 0.f;
#pragma unroll
    for (int c = 0; c < 8; ++c) s += part[(((long)bh * 8 + c) << 14) + j];
    kvt[i] = f2bf(s);
  }
}

// ---- K row sums: Ksum[bh*128+d] = sum_t KT[(h*128+d)*M_TOK + b*4096 + t] ----
__global__ __launch_bounds__(256) void ksum_kernel(const unsigned short* __restrict__ KT,
                                                   float* __restrict__ ksum) {
  int gr = blockIdx.x * 4 + (threadIdx.x >> 6);    // 0..8191 = bh*128+d
  int lane = threadIdx.x & 63;
  int bh = gr >> 7, d = gr & 127;
  int b = bh >> 4, h = bh & 15;
  const unsigned short* p = KT + (long)(h * DKH + d) * M_TOK + (long)b * SEQ;
  float s = 0.f;
#pragma unroll
  for (int i = 0; i < 8; ++i) {
    uint4 v = *reinterpret_cast<const uint4*>(p + (i * 64 + lane) * 8);
    unsigned w[4] = {v.x, v.y, v.z, v.w};
#pragma unroll
    for (int j = 0; j < 4; ++j) {
      s += bf2f((unsigned short)(w[j] & 0xffff));
      s += bf2f((unsigned short)(w[j] >> 16));
    }
  }
#pragma unroll
  for (int o = 32; o > 0; o >>= 1) s += __shfl_down(s, o);
  if (lane == 0) ksum[gr] = s;
}

// ---- qsum[bh*4096+s] = sum_d Q[(b*4096+s)*2048 + h*128 + d] * Ksum[bh*128+d]
__global__ __launch_bounds__(256) void qsum_kernel(const unsigned short* __restrict__ Q,
                                                   const float* __restrict__ ksum,
                                                   float* __restrict__ qsum) {
  int gr = blockIdx.x * 4 + (threadIdx.x >> 6);    // 0..262143 = bh*4096 + s
  int lane = threadIdx.x & 63;
  int bh = gr >> 12, s = gr & 4095;
  int b = bh >> 4, h = bh & 15;
  const unsigned short* q = Q + ((long)b * SEQ + s) * D_MODEL + h * DKH + lane * 2;
  unsigned u = *reinterpret_cast<const unsigned*>(q);
  const float* ks = ksum + bh * DKH + lane * 2;
  float sum = bf2f((unsigned short)(u & 0xffff)) * ks[0] +
              bf2f((unsigned short)(u >> 16)) * ks[1];
#pragma unroll
  for (int o = 32; o > 0; o >>= 1) sum += __shfl_down(sum, o);
  if (lane == 0) qsum[gr] = sum;
}

// ---- QKV: per (bh), C[s,e] = sum_d Q[s,d]*KVT[e,d]; divide by qsum ---------
__global__ __launch_bounds__(256) void qkv_kernel(const unsigned short* __restrict__ Q,
                                                  const unsigned short* __restrict__ KVT,
                                                  const float* __restrict__ qsum,
                                                  unsigned short* __restrict__ attn) {
  __shared__ unsigned short lA[128 * 64], lB[128 * 64];
  const int z = blockIdx.z, b = z >> 4, h = z & 15;
  const long m0 = (long)blockIdx.y * 128;
  const unsigned short* A  = Q + ((long)b * SEQ + m0) * D_MODEL + h * DKH;
  const unsigned short* Bm = KVT + (long)z * (DKH * DKH);
  f32x4 acc[4][4];
  ACC_INIT(acc);
  gemm_mainloop(A, D_MODEL, Bm, DKH, DKH, lA, lB, acc);
  const int lane = threadIdx.x & 63, wid = threadIdx.x >> 6;
  const int wr = wid >> 1, wc = wid & 1, lr = lane & 15, lh = lane >> 4;
#pragma unroll
  for (int m = 0; m < 4; ++m)
#pragma unroll
    for (int n = 0; n < 4; ++n)
#pragma unroll
      for (int r = 0; r < 4; ++r) {
        long row = m0 + wr * 64 + m * 16 + lh * 4 + r;   // s in [0,4096)
        int  col = wc * 64 + n * 16 + lr;                // e in [0,128)
        float dnm = qsum[(long)z * SEQ + row] + 1e-8f;
        float v = acc[m][n][r] / dnm;
        attn[((long)b * SEQ + row) * D_MODEL + h * DKH + col] = f2bf(v);
      }
}

// ---- workspace layout (bytes) ----------------------------------------------
#define OFF_XB   0L
#define OFF_WQ   (OFF_XB + (long)M_TOK * D_MODEL * 2)          // 67108864
#define OFF_WK   (OFF_WQ + (long)D_MODEL * D_MODEL * 2)
#define OFF_WV   (OFF_WK + (long)D_MODEL * D_MODEL * 2)
#define OFF_WO   (OFF_WV + (long)D_MODEL * D_MODEL * 2)
#define OFF_QB   (OFF_WO + (long)D_MODEL * D_MODEL * 2)
#define OFF_KT   (OFF_QB + (long)M_TOK * D_MODEL * 2)
#define OFF_VT   (OFF_KT + (long)M_TOK * D_MODEL * 2)
#define OFF_PART (OFF_VT + (long)M_TOK * D_MODEL * 2)
#define OFF_KVT  (OFF_PART + (long)512 * DKH * DKH * 4)
#define OFF_KSUM (OFF_KVT + (long)NBH * DKH * DKH * 2)
#define OFF_QSUM (OFF_KSUM + (long)NBH * DKH * 4)
#define OFF_ATTN OFF_XB   // alias: x_bf16 dead after V^T projection

extern "C" void kernel_launch(void* const* d_in, const int* in_sizes, int n_in,
                              void* d_out, int out_size, void* d_ws, size_t ws_size,
                              hipStream_t stream) {
  const float* x  = (const float*)d_in[0];
  const float* wq = (const float*)d_in[1];
  const float* bq = (const float*)d_in[2];
  const float* wk = (const float*)d_in[3];
  const float* bk = (const float*)d_in[4];
  const float* wv = (const float*)d_in[5];
  const float* bv = (const float*)d_in[6];
  const float* wo = (const float*)d_in[7];
  const float* bo = (const float*)d_in[8];

  char* ws = (char*)d_ws;
  unsigned short* xb   = (unsigned short*)(ws + OFF_XB);
  unsigned short* wqb  = (unsigned short*)(ws + OFF_WQ);
  unsigned short* wkb  = (unsigned short*)(ws + OFF_WK);
  unsigned short* wvb  = (unsigned short*)(ws + OFF_WV);
  unsigned short* wob  = (unsigned short*)(ws + OFF_WO);
  unsigned short* Qb   = (unsigned short*)(ws + OFF_QB);
  unsigned short* KTb  = (unsigned short*)(ws + OFF_KT);
  unsigned short* VTb  = (unsigned short*)(ws + OFF_VT);
  float*          part = (float*)(ws + OFF_PART);
  unsigned short* KVTb = (unsigned short*)(ws + OFF_KVT);
  float*          ksum = (float*)(ws + OFF_KSUM);
  float*          qsum = (float*)(ws + OFF_QSUM);
  unsigned short* attn = (unsigned short*)(ws + OFF_ATTN);

  dim3 blk(256);

  // fp32 -> bf16
  convert_f2bf_kernel<<<(M_TOK * D_MODEL / 4) / 256, blk, 0, stream>>>(x, xb, M_TOK * D_MODEL / 4);
  convert_f2bf_kernel<<<(D_MODEL * D_MODEL / 4) / 256, blk, 0, stream>>>(wq, wqb, D_MODEL * D_MODEL / 4);
  convert_f2bf_kernel<<<(D_MODEL * D_MODEL / 4) / 256, blk, 0, stream>>>(wk, wkb, D_MODEL * D_MODEL / 4);
  convert_f2bf_kernel<<<(D_MODEL * D_MODEL / 4) / 256, blk, 0, stream>>>(wv, wvb, D_MODEL * D_MODEL / 4);
  convert_f2bf_kernel<<<(D_MODEL * D_MODEL / 4) / 256, blk, 0, stream>>>(wo, wob, D_MODEL * D_MODEL / 4);

  // Q = elu(x@Wq^T + bq)+1                       (M_TOK x 2048)
  gemm_nt_kernel<0><<<dim3(D_MODEL / 128, M_TOK / 128), blk, 0, stream>>>(
      xb, D_MODEL, wqb, D_MODEL, Qb, D_MODEL, bq, D_MODEL);
  // K^T = elu(Wk@x^T + bk)+1  (2048 x M_TOK), V^T = Wv@x^T + bv
  gemm_nt_kernel<1><<<dim3(M_TOK / 128, D_MODEL / 128), blk, 0, stream>>>(
      wkb, D_MODEL, xb, D_MODEL, KTb, M_TOK, bk, D_MODEL);
  gemm_nt_kernel<2><<<dim3(M_TOK / 128, D_MODEL / 128), blk, 0, stream>>>(
      wvb, D_MODEL, xb, D_MODEL, VTb, M_TOK, bv, D_MODEL);

  // KV^T per (b,h) via split-K partials + reduce
  kvt_partial_kernel<<<512, blk, 0, stream>>>(VTb, KTb, part);
  reduce_kvt_kernel<<<(NBH * DKH * DKH) / 256, blk, 0, stream>>>(part, KVTb);

  // K_sum and per-row denominators
  ksum_kernel<<<(NBH * DKH) / 4, blk, 0, stream>>>(KTb, ksum);
  qsum_kernel<<<(NBH * SEQ) / 4, blk, 0, stream>>>(Qb, ksum, qsum);

  // attn = (Q @ KV) / (Q . Ksum + 1e-8)   -> bf16 (aliases xb)
  qkv_kernel<<<dim3(1, SEQ / 128, NBH), blk, 0, stream>>>(Qb, KVTb, qsum, attn);

  // out = attn @ Wo^T + bo  -> fp32
  gemm_nt_kernel<3><<<dim3(D_MODEL / 128, M_TOK / 128), blk, 0, stream>>>(
      attn, D_MODEL, wob, D_MODEL, d_out, D_MODEL, bo, D_MODEL);
}

// Round 2
// 980.424 us; speedup vs baseline: 1.0594x; 1.0594x over previous
//
#include <hip/hip_runtime.h>

// Linear attention (elu+1 feature map), B=4 S=4096 D=2048 H=16 dk=128.
// bf16 MFMA, fp32 accumulate. Round 2: m97-structure staging —
// direct global->LDS async copy (global_load_lds width=16), linear LDS layout.

#define D_MODEL 2048
#define SEQ     4096
#define BATCH   4
#define HEADS   16
#define DKH     128
#define M_TOK   16384   // BATCH*SEQ
#define NBH     64      // BATCH*HEADS

using frag8 = __attribute__((ext_vector_type(8))) short;   // 8 bf16 (4 VGPRs)
using f32x4 = __attribute__((ext_vector_type(4))) float;   // 4 fp32 acc

typedef __attribute__((address_space(1))) const unsigned int g_u32;
typedef __attribute__((address_space(3))) unsigned int       l_u32;

__device__ __forceinline__ unsigned short f2bf(float f) {
  unsigned u = __float_as_uint(f);
  u = u + 0x7fffu + ((u >> 16) & 1u);   // round-to-nearest-even
  return (unsigned short)(u >> 16);
}
__device__ __forceinline__ float bf2f(unsigned short h) {
  return __uint_as_float(((unsigned)h) << 16);
}

// ---- fp32 -> bf16 convert (vectorized) --------------------------------------
__global__ __launch_bounds__(256) void convert_f2bf_kernel(
    const float* __restrict__ in, unsigned short* __restrict__ out, int n4) {
  int i = blockIdx.x * 256 + threadIdx.x;
  if (i < n4) {
    float4 v = reinterpret_cast<const float4*>(in)[i];
    ushort4 o;
    o.x = f2bf(v.x); o.y = f2bf(v.y); o.z = f2bf(v.z); o.w = f2bf(v.w);
    reinterpret_cast<ushort4*>(out)[i] = o;
  }
}

// ---- async staging: 128x64 bf16 tile (16 KB), linear LDS ------------------
// 256 threads = 4 waves; wave w covers LDS chunks [4w,4w+4) of 1 KB each.
// Chunk c = 8 rows starting at row 8c; lane l -> row 8c + l/8, col (l&7)*8.
// LDS dest per instruction is wave-uniform (chunk base); HW adds lane*16.
__device__ __forceinline__ void stage_tile(const unsigned short* __restrict__ G,
                                           long ld, unsigned short* __restrict__ L) {
  const int w = threadIdx.x >> 6, l = threadIdx.x & 63;
#pragma unroll
  for (int r = 0; r < 4; ++r) {
    const int chunk = w * 4 + r;
    const int row = chunk * 8 + (l >> 3);
    const int col = (l & 7) * 8;
    __builtin_amdgcn_global_load_lds((g_u32*)(G + (long)row * ld + col),
                                     (l_u32*)(L + chunk * 512), 16, 0, 0);
  }
}

// ---- shared GEMM core: C[128x128] += A(128xK) * B(128xK)^T, bf16, NT -------
// 256 threads = 4 waves in 2x2; per-wave 64x64 = 4x4 fragments of 16x16x32.
__device__ __forceinline__ void gemm_mainloop(const unsigned short* __restrict__ A, long lda,
                                              const unsigned short* __restrict__ B, long ldb,
                                              int K, unsigned short* lA, unsigned short* lB,
                                              f32x4 acc[4][4]) {
  const int lane = threadIdx.x & 63;
  const int wid  = threadIdx.x >> 6;
  const int wr = wid >> 1, wc = wid & 1;
  const int lr = lane & 15, lh = lane >> 4;
  for (int k0 = 0; k0 < K; k0 += 64) {
    stage_tile(A + k0, lda, lA);
    stage_tile(B + k0, ldb, lB);
    __syncthreads();
#pragma unroll
    for (int kk = 0; kk < 64; kk += 32) {
      frag8 av[4], bv[4];
#pragma unroll
      for (int m = 0; m < 4; ++m)
        av[m] = *reinterpret_cast<const frag8*>(lA + (wr * 64 + m * 16 + lr) * 64 + kk + lh * 8);
#pragma unroll
      for (int n = 0; n < 4; ++n)
        bv[n] = *reinterpret_cast<const frag8*>(lB + (wc * 64 + n * 16 + lr) * 64 + kk + lh * 8);
#pragma unroll
      for (int m = 0; m < 4; ++m)
#pragma unroll
        for (int n = 0; n < 4; ++n)
          acc[m][n] = __builtin_amdgcn_mfma_f32_16x16x32_bf16(av[m], bv[n], acc[m][n], 0, 0, 0);
    }
    __syncthreads();
  }
}

#define ACC_INIT(acc)                                   \
  _Pragma("unroll") for (int m_ = 0; m_ < 4; ++m_)      \
  _Pragma("unroll") for (int n_ = 0; n_ < 4; ++n_)      \
      acc[m_][n_] = (f32x4){0.f, 0.f, 0.f, 0.f};

// MODE: 0 = elu(v+bias[col])+1 -> bf16   (Q projection)
//       1 = elu(v+bias[row])+1 -> bf16   (K^T projection, bias is per-feature=row)
//       2 = v+bias[row]        -> bf16   (V^T projection)
//       3 = v+bias[col]        -> f32    (final output projection)
template <int MODE>
__global__ __launch_bounds__(256) void gemm_nt_kernel(
    const unsigned short* __restrict__ A, long lda,
    const unsigned short* __restrict__ Bm, long ldb,
    void* __restrict__ Cv, long ldc,
    const float* __restrict__ bias, int K) {
  __shared__ unsigned short lA[128 * 64], lB[128 * 64];
  const long m0 = (long)blockIdx.y * 128, n0 = (long)blockIdx.x * 128;
  f32x4 acc[4][4];
  ACC_INIT(acc);
  gemm_mainloop(A + m0 * lda, lda, Bm + n0 * ldb, ldb, K, lA, lB, acc);
  const int lane = threadIdx.x & 63, wid = threadIdx.x >> 6;
  const int wr = wid >> 1, wc = wid & 1, lr = lane & 15, lh = lane >> 4;
#pragma unroll
  for (int m = 0; m < 4; ++m)
#pragma unroll
    for (int n = 0; n < 4; ++n)
#pragma unroll
      for (int r = 0; r < 4; ++r) {
        long row = m0 + wr * 64 + m * 16 + lh * 4 + r;
        long col = n0 + wc * 64 + n * 16 + lr;
        float v = acc[m][n][r];
        if (MODE == 0) {
          v += bias[col]; v = v > 0.f ? v + 1.f : __expf(v);
          ((unsigned short*)Cv)[row * ldc + col] = f2bf(v);
        } else if (MODE == 1) {
          v += bias[row]; v = v > 0.f ? v + 1.f : __expf(v);
          ((unsigned short*)Cv)[row * ldc + col] = f2bf(v);
        } else if (MODE == 2) {
          v += bias[row];
          ((unsigned short*)Cv)[row * ldc + col] = f2bf(v);
        } else {
          v += bias[col];
          ((float*)Cv)[row * ldc + col] = v;
        }
      }
}

// ---- KV^T partials: per (bh, chunk) C[e,d] = sum_t V[t,e]K[t,d] over 512 t --
__global__ __launch_bounds__(256) void kvt_partial_kernel(
    const unsigned short* __restrict__ VT, const unsigned short* __restrict__ KT,
    float* __restrict__ part) {
  __shared__ unsigned short lA[128 * 64], lB[128 * 64];
  const int z = blockIdx.x;            // 0..511 = bh*8 + chunk
  const int bh = z >> 3, c = z & 7;
  const int b = bh >> 4, h = bh & 15;
  const long tOff = (long)b * SEQ + (long)c * 512;
  const unsigned short* A  = VT + (long)(h * DKH) * M_TOK + tOff;
  const unsigned short* Bm = KT + (long)(h * DKH) * M_TOK + tOff;
  f32x4 acc[4][4];
  ACC_INIT(acc);
  gemm_mainloop(A, M_TOK, Bm, M_TOK, 512, lA, lB, acc);
  const int lane = threadIdx.x & 63, wid = threadIdx.x >> 6;
  const int wr = wid >> 1, wc = wid & 1, lr = lane & 15, lh = lane >> 4;
  float* out = part + (long)z * (DKH * DKH);
#pragma unroll
  for (int m = 0; m < 4; ++m)
#pragma unroll
    for (int n = 0; n < 4; ++n)
#pragma unroll
      for (int r = 0; r < 4; ++r) {
        int row = wr * 64 + m * 16 + lh * 4 + r;   // e
        int col = wc * 64 + n * 16 + lr;           // d
        out[row * DKH + col] = acc[m][n][r];
      }
}

__global__ __launch_bounds__(256) void reduce_kvt_kernel(
    const float* __restrict__ part, unsigned short* __restrict__ kvt) {
  int i = blockIdx.x * 256 + threadIdx.x;          // over 64*16384
  if (i < NBH * DKH * DKH) {
    int bh = i >> 14, j = i & 16383;
    float s = 0.f;
#pragma unroll
    for (int c = 0; c < 8; ++c) s += part[(((long)bh * 8 + c) << 14) + j];
    kvt[i] = f2bf(s);
  }
}

// ---- K row sums: Ksum[bh*128+d] = sum_t KT[(h*128+d)*M_TOK + b*4096 + t] ----
__global__ __launch_bounds__(256) void ksum_kernel(const unsigned short* __restrict__ KT,
                                                   float* __restrict__ ksum) {
  int gr = blockIdx.x * 4 + (threadIdx.x >> 6);    // 0..8191 = bh*128+d
  int lane = threadIdx.x & 63;
  int bh = gr >> 7, d = gr & 127;
  int b = bh >> 4, h = bh & 15;
  const unsigned short* p = KT + (long)(h * DKH + d) * M_TOK + (long)b * SEQ;
  float s = 0.f;
#pragma unroll
  for (int i = 0; i < 8; ++i) {
    uint4 v = *reinterpret_cast<const uint4*>(p + (i * 64 + lane) * 8);
    unsigned w[4] = {v.x, v.y, v.z, v.w};
#pragma unroll
    for (int j = 0; j < 4; ++j) {
      s += bf2f((unsigned short)(w[j] & 0xffff));
      s += bf2f((unsigned short)(w[j] >> 16));
    }
  }
#pragma unroll
  for (int o = 32; o > 0; o >>= 1) s += __shfl_down(s, o);
  if (lane == 0) ksum[gr] = s;
}

// ---- qsum[bh*4096+s] = sum_d Q[(b*4096+s)*2048 + h*128 + d] * Ksum[bh*128+d]
__global__ __launch_bounds__(256) void qsum_kernel(const unsigned short* __restrict__ Q,
                                                   const float* __restrict__ ksum,
                                                   float* __restrict__ qsum) {
  int gr = blockIdx.x * 4 + (threadIdx.x >> 6);    // 0..262143 = bh*4096 + s
  int lane = threadIdx.x & 63;
  int bh = gr >> 12, s = gr & 4095;
  int b = bh >> 4, h = bh & 15;
  const unsigned short* q = Q + ((long)b * SEQ + s) * D_MODEL + h * DKH + lane * 2;
  unsigned u = *reinterpret_cast<const unsigned*>(q);
  const float* ks = ksum + bh * DKH + lane * 2;
  float sum = bf2f((unsigned short)(u & 0xffff)) * ks[0] +
              bf2f((unsigned short)(u >> 16)) * ks[1];
#pragma unroll
  for (int o = 32; o > 0; o >>= 1) sum += __shfl_down(sum, o);
  if (lane == 0) qsum[gr] = sum;
}

// ---- QKV: per (bh), C[s,e] = sum_d Q[s,d]*KVT[e,d]; divide by qsum ---------
__global__ __launch_bounds__(256) void qkv_kernel(const unsigned short* __restrict__ Q,
                                                  const unsigned short* __restrict__ KVT,
                                                  const float* __restrict__ qsum,
                                                  unsigned short* __restrict__ attn) {
  __shared__ unsigned short lA[128 * 64], lB[128 * 64];
  const int z = blockIdx.z, b = z >> 4, h = z & 15;
  const long m0 = (long)blockIdx.y * 128;
  const unsigned short* A  = Q + ((long)b * SEQ + m0) * D_MODEL + h * DKH;
  const unsigned short* Bm = KVT + (long)z * (DKH * DKH);
  f32x4 acc[4][4];
  ACC_INIT(acc);
  gemm_mainloop(A, D_MODEL, Bm, DKH, DKH, lA, lB, acc);
  const int lane = threadIdx.x & 63, wid = threadIdx.x >> 6;
  const int wr = wid >> 1, wc = wid & 1, lr = lane & 15, lh = lane >> 4;
#pragma unroll
  for (int m = 0; m < 4; ++m)
#pragma unroll
    for (int n = 0; n < 4; ++n)
#pragma unroll
      for (int r = 0; r < 4; ++r) {
        long row = m0 + wr * 64 + m * 16 + lh * 4 + r;   // s in [0,4096)
        int  col = wc * 64 + n * 16 + lr;                // e in [0,128)
        float dnm = qsum[(long)z * SEQ + row] + 1e-8f;
        float v = acc[m][n][r] / dnm;
        attn[((long)b * SEQ + row) * D_MODEL + h * DKH + col] = f2bf(v);
      }
}

// ---- workspace layout (bytes) ----------------------------------------------
#define OFF_XB   0L
#define OFF_WQ   (OFF_XB + (long)M_TOK * D_MODEL * 2)          // 67108864
#define OFF_WK   (OFF_WQ + (long)D_MODEL * D_MODEL * 2)
#define OFF_WV   (OFF_WK + (long)D_MODEL * D_MODEL * 2)
#define OFF_WO   (OFF_WV + (long)D_MODEL * D_MODEL * 2)
#define OFF_QB   (OFF_WO + (long)D_MODEL * D_MODEL * 2)
#define OFF_KT   (OFF_QB + (long)M_TOK * D_MODEL * 2)
#define OFF_VT   (OFF_KT + (long)M_TOK * D_MODEL * 2)
#define OFF_PART (OFF_VT + (long)M_TOK * D_MODEL * 2)
#define OFF_KVT  (OFF_PART + (long)512 * DKH * DKH * 4)
#define OFF_KSUM (OFF_KVT + (long)NBH * DKH * DKH * 2)
#define OFF_QSUM (OFF_KSUM + (long)NBH * DKH * 4)
#define OFF_ATTN OFF_XB   // alias: x_bf16 dead after V^T projection

extern "C" void kernel_launch(void* const* d_in, const int* in_sizes, int n_in,
                              void* d_out, int out_size, void* d_ws, size_t ws_size,
                              hipStream_t stream) {
  const float* x  = (const float*)d_in[0];
  const float* wq = (const float*)d_in[1];
  const float* bq = (const float*)d_in[2];
  const float* wk = (const float*)d_in[3];
  const float* bk = (const float*)d_in[4];
  const float* wv = (const float*)d_in[5];
  const float* bv = (const float*)d_in[6];
  const float* wo = (const float*)d_in[7];
  const float* bo = (const float*)d_in[8];

  char* ws = (char*)d_ws;
  unsigned short* xb   = (unsigned short*)(ws + OFF_XB);
  unsigned short* wqb  = (unsigned short*)(ws + OFF_WQ);
  unsigned short* wkb  = (unsigned short*)(ws + OFF_WK);
  unsigned short* wvb  = (unsigned short*)(ws + OFF_WV);
  unsigned short* wob  = (unsigned short*)(ws + OFF_WO);
  unsigned short* Qb   = (unsigned short*)(ws + OFF_QB);
  unsigned short* KTb  = (unsigned short*)(ws + OFF_KT);
  unsigned short* VTb  = (unsigned short*)(ws + OFF_VT);
  float*          part = (float*)(ws + OFF_PART);
  unsigned short* KVTb = (unsigned short*)(ws + OFF_KVT);
  float*          ksum = (float*)(ws + OFF_KSUM);
  float*          qsum = (float*)(ws + OFF_QSUM);
  unsigned short* attn = (unsigned short*)(ws + OFF_ATTN);

  dim3 blk(256);

  // fp32 -> bf16
  convert_f2bf_kernel<<<(M_TOK * D_MODEL / 4) / 256, blk, 0, stream>>>(x, xb, M_TOK * D_MODEL / 4);
  convert_f2bf_kernel<<<(D_MODEL * D_MODEL / 4) / 256, blk, 0, stream>>>(wq, wqb, D_MODEL * D_MODEL / 4);
  convert_f2bf_kernel<<<(D_MODEL * D_MODEL / 4) / 256, blk, 0, stream>>>(wk, wkb, D_MODEL * D_MODEL / 4);
  convert_f2bf_kernel<<<(D_MODEL * D_MODEL / 4) / 256, blk, 0, stream>>>(wv, wvb, D_MODEL * D_MODEL / 4);
  convert_f2bf_kernel<<<(D_MODEL * D_MODEL / 4) / 256, blk, 0, stream>>>(wo, wob, D_MODEL * D_MODEL / 4);

  // Q = elu(x@Wq^T + bq)+1                       (M_TOK x 2048)
  gemm_nt_kernel<0><<<dim3(D_MODEL / 128, M_TOK / 128), blk, 0, stream>>>(
      xb, D_MODEL, wqb, D_MODEL, Qb, D_MODEL, bq, D_MODEL);
  // K^T = elu(Wk@x^T + bk)+1  (2048 x M_TOK), V^T = Wv@x^T + bv
  gemm_nt_kernel<1><<<dim3(M_TOK / 128, D_MODEL / 128), blk, 0, stream>>>(
      wkb, D_MODEL, xb, D_MODEL, KTb, M_TOK, bk, D_MODEL);
  gemm_nt_kernel<2><<<dim3(M_TOK / 128, D_MODEL / 128), blk, 0, stream>>>(
      wvb, D_MODEL, xb, D_MODEL, VTb, M_TOK, bv, D_MODEL);

  // KV^T per (b,h) via split-K partials + reduce
  kvt_partial_kernel<<<512, blk, 0, stream>>>(VTb, KTb, part);
  reduce_kvt_kernel<<<(NBH * DKH * DKH) / 256, blk, 0, stream>>>(part, KVTb);

  // K_sum and per-row denominators
  ksum_kernel<<<(NBH * DKH) / 4, blk, 0, stream>>>(KTb, ksum);
  qsum_kernel<<<(NBH * SEQ) / 4, blk, 0, stream>>>(Qb, ksum, qsum);

  // attn = (Q @ KV) / (Q . Ksum + 1e-8)   -> bf16 (aliases xb)
  qkv_kernel<<<dim3(1, SEQ / 128, NBH), blk, 0, stream>>>(Qb, KVTb, qsum, attn);

  // out = attn @ Wo^T + bo  -> fp32
  gemm_nt_kernel<3><<<dim3(D_MODEL / 128, M_TOK / 128), blk, 0, stream>>>(
      attn, D_MODEL, wob, D_MODEL, d_out, D_MODEL, bo, D_MODEL);
}

// Round 3
// 804.983 us; speedup vs baseline: 1.2903x; 1.2179x over previous
//
#include <hip/hip_runtime.h>

// Linear attention (elu+1 feature map), B=4 S=4096 D=2048 H=16 dk=128.
// bf16 MFMA, fp32 accumulate.
// Round 3: 256x256 phased GEMM (T2 swizzle + T3/T4 counted-vmcnt pipeline + T5
// setprio) for the four big projections; attention core keeps the 128^2 path.

#define D_MODEL 2048
#define SEQ     4096
#define BATCH   4
#define HEADS   16
#define DKH     128
#define M_TOK   16384   // BATCH*SEQ
#define NBH     64      // BATCH*HEADS

using frag8 = __attribute__((ext_vector_type(8))) short;   // 8 bf16 (4 VGPRs)
using f32x4 = __attribute__((ext_vector_type(4))) float;   // 4 fp32 acc

typedef __attribute__((address_space(1))) const unsigned int g_u32;
typedef __attribute__((address_space(3))) unsigned int       l_u32;

__device__ __forceinline__ unsigned short f2bf(float f) {
  unsigned u = __float_as_uint(f);
  u = u + 0x7fffu + ((u >> 16) & 1u);   // round-to-nearest-even
  return (unsigned short)(u >> 16);
}
__device__ __forceinline__ float bf2f(unsigned short h) {
  return __uint_as_float(((unsigned)h) << 16);
}

// ---- fp32 -> bf16 convert (vectorized) --------------------------------------
__global__ __launch_bounds__(256) void convert_f2bf_kernel(
    const float* __restrict__ in, unsigned short* __restrict__ out, int n4) {
  int i = blockIdx.x * 256 + threadIdx.x;
  if (i < n4) {
    float4 v = reinterpret_cast<const float4*>(in)[i];
    ushort4 o;
    o.x = f2bf(v.x); o.y = f2bf(v.y); o.z = f2bf(v.z); o.w = f2bf(v.w);
    reinterpret_cast<ushort4*>(out)[i] = o;
  }
}

// ============================================================================
// 256x256 phased GEMM: C = A(256xK) * B(256xK)^T, bf16, NT. 512 thr = 8 waves
// (2M x 4N); per-wave 128x64 out = 8x4 frags of 16x16x32. BK=32, LDS 64 KB
// double-buffered, XOR-swizzled (c16 ^= row&3). Stage t+2 into the buffer
// freed by tile t (after lgkm-drain + barrier) -> race-free counted pipeline.
// ============================================================================

// stage a 256x32 bf16 tile (16 KB) -> LDS linear (2 global_load_lds / thread).
// Lane l of wave w, round q: LDS slot (row = q*128 + w*16 + l/4, quad l&3);
// global source quad = (l&3) ^ (row&3)  (inverse swizzle on the source).
__device__ __forceinline__ void stage256x32(const unsigned short* __restrict__ G,
                                            long ld, unsigned short* __restrict__ L) {
  const int t = threadIdx.x;
  const int w = t >> 6, l = t & 63;
  const int rw = l >> 2;
  const int c16s = (l & 3) ^ (rw & 3);
#pragma unroll
  for (int q = 0; q < 2; ++q) {
    const int row = q * 128 + w * 16 + rw;
    __builtin_amdgcn_global_load_lds((g_u32*)(G + (long)row * ld + c16s * 8),
                                     (l_u32*)(L + q * 4096 + w * 512), 16, 0, 0);
  }
}

// MODE: 0 = elu(v+bias[col])+1 -> bf16   (Q projection)
//       1 = elu(v+bias[row])+1 -> bf16   (K^T projection)
//       2 = v+bias[row]        -> bf16   (V^T projection)
//       3 = v+bias[col]        -> f32    (final output projection)
template <int MODE>
__global__ __launch_bounds__(512) void gemm256_nt_kernel(
    const unsigned short* __restrict__ A, long lda,
    const unsigned short* __restrict__ Bm, long ldb,
    void* __restrict__ Cv, long ldc,
    const float* __restrict__ bias, int K) {
  __shared__ unsigned short sh[32768];   // 64 KB: [parity][A 8192 | B 8192] elems
  const int lane = threadIdx.x & 63, wid = threadIdx.x >> 6;
  const int wm = wid >> 2, wn = wid & 3;
  const int lr = lane & 15, lh = lane >> 4;
  const long m0 = (long)blockIdx.y * 256, n0 = (long)blockIdx.x * 256;
  const unsigned short* Ablk = A + m0 * lda;
  const unsigned short* Bblk = Bm + n0 * ldb;
  const int NT = K >> 5;

  f32x4 acc[8][4];
#pragma unroll
  for (int m = 0; m < 8; ++m)
#pragma unroll
    for (int n = 0; n < 4; ++n) acc[m][n] = (f32x4){0.f, 0.f, 0.f, 0.f};

  // prologue: stage tiles 0,1 (8 loads/wave); wait oldest 4 (tile 0)
  stage256x32(Ablk,      lda, sh);
  stage256x32(Bblk,      ldb, sh + 8192);
  stage256x32(Ablk + 32, lda, sh + 16384);
  stage256x32(Bblk + 32, ldb, sh + 16384 + 8192);
  asm volatile("s_waitcnt vmcnt(4)" ::: "memory");
  __builtin_amdgcn_s_barrier();

  const int alx = (lh ^ (lr & 3)) * 8;   // swizzled quad offset (elems)

  for (int t = 0; t < NT; ++t) {
    const int cur = t & 1;
    const unsigned short* lA = sh + cur * 16384;
    const unsigned short* lB = lA + 8192;
    frag8 av[4], bv[4];
    // ---- phase 0 (m 0..3) ----
#pragma unroll
    for (int i = 0; i < 4; ++i)
      av[i] = *(const frag8*)(lA + (wm * 128 + i * 16 + lr) * 32 + alx);
#pragma unroll
    for (int n = 0; n < 4; ++n)
      bv[n] = *(const frag8*)(lB + (wn * 64 + n * 16 + lr) * 32 + alx);
    __builtin_amdgcn_s_barrier();
    asm volatile("s_waitcnt lgkmcnt(0)" ::: "memory");
    __builtin_amdgcn_sched_barrier(0);
    __builtin_amdgcn_s_setprio(1);
#pragma unroll
    for (int i = 0; i < 4; ++i)
#pragma unroll
      for (int n = 0; n < 4; ++n)
        acc[i][n] = __builtin_amdgcn_mfma_f32_16x16x32_bf16(av[i], bv[n], acc[i][n], 0, 0, 0);
    __builtin_amdgcn_s_setprio(0);
    __builtin_amdgcn_s_barrier();
    // ---- phase 1 (m 4..7); stage t+2 into the buffer tile t just freed ----
#pragma unroll
    for (int i = 0; i < 4; ++i)
      av[i] = *(const frag8*)(lA + (wm * 128 + 64 + i * 16 + lr) * 32 + alx);
    asm volatile("s_waitcnt lgkmcnt(0)" ::: "memory");   // my reads of buf[cur] done
    __builtin_amdgcn_sched_barrier(0);
    __builtin_amdgcn_s_barrier();                        // ALL waves' reads done
    __builtin_amdgcn_sched_barrier(0);
    if (t + 2 < NT) {
      unsigned short* dst = (unsigned short*)sh + cur * 16384;
      stage256x32(Ablk + (long)(t + 2) * 32, lda, dst);
      stage256x32(Bblk + (long)(t + 2) * 32, ldb, dst + 8192);
    }
    __builtin_amdgcn_s_setprio(1);
#pragma unroll
    for (int i = 0; i < 4; ++i)
#pragma unroll
      for (int n = 0; n < 4; ++n)
        acc[4 + i][n] = __builtin_amdgcn_mfma_f32_16x16x32_bf16(av[i], bv[n], acc[4 + i][n], 0, 0, 0);
    __builtin_amdgcn_s_setprio(0);
    if (t + 2 < NT) asm volatile("s_waitcnt vmcnt(4)" ::: "memory");  // t+1 landed
    else            asm volatile("s_waitcnt vmcnt(0)" ::: "memory");  // drain tail
    __builtin_amdgcn_s_barrier();
  }

  // epilogue
#pragma unroll
  for (int m = 0; m < 8; ++m)
#pragma unroll
    for (int n = 0; n < 4; ++n)
#pragma unroll
      for (int r = 0; r < 4; ++r) {
        long row = m0 + wm * 128 + m * 16 + lh * 4 + r;
        long col = n0 + wn * 64 + n * 16 + lr;
        float v = acc[m][n][r];
        if (MODE == 0) {
          v += bias[col]; v = v > 0.f ? v + 1.f : __expf(v);
          ((unsigned short*)Cv)[row * ldc + col] = f2bf(v);
        } else if (MODE == 1) {
          v += bias[row]; v = v > 0.f ? v + 1.f : __expf(v);
          ((unsigned short*)Cv)[row * ldc + col] = f2bf(v);
        } else if (MODE == 2) {
          v += bias[row];
          ((unsigned short*)Cv)[row * ldc + col] = f2bf(v);
        } else {
          v += bias[col];
          ((float*)Cv)[row * ldc + col] = v;
        }
      }
}

// ============================================================================
// 128x128 path (attention core: KV^T partials, QKV) — unchanged from round 2.
// ============================================================================
__device__ __forceinline__ void stage_tile(const unsigned short* __restrict__ G,
                                           long ld, unsigned short* __restrict__ L) {
  const int w = threadIdx.x >> 6, l = threadIdx.x & 63;
#pragma unroll
  for (int r = 0; r < 4; ++r) {
    const int chunk = w * 4 + r;
    const int row = chunk * 8 + (l >> 3);
    const int col = (l & 7) * 8;
    __builtin_amdgcn_global_load_lds((g_u32*)(G + (long)row * ld + col),
                                     (l_u32*)(L + chunk * 512), 16, 0, 0);
  }
}

__device__ __forceinline__ void gemm_mainloop(const unsigned short* __restrict__ A, long lda,
                                              const unsigned short* __restrict__ B, long ldb,
                                              int K, unsigned short* lA, unsigned short* lB,
                                              f32x4 acc[4][4]) {
  const int lane = threadIdx.x & 63;
  const int wid  = threadIdx.x >> 6;
  const int wr = wid >> 1, wc = wid & 1;
  const int lr = lane & 15, lh = lane >> 4;
  for (int k0 = 0; k0 < K; k0 += 64) {
    stage_tile(A + k0, lda, lA);
    stage_tile(B + k0, ldb, lB);
    __syncthreads();
#pragma unroll
    for (int kk = 0; kk < 64; kk += 32) {
      frag8 av[4], bv[4];
#pragma unroll
      for (int m = 0; m < 4; ++m)
        av[m] = *reinterpret_cast<const frag8*>(lA + (wr * 64 + m * 16 + lr) * 64 + kk + lh * 8);
#pragma unroll
      for (int n = 0; n < 4; ++n)
        bv[n] = *reinterpret_cast<const frag8*>(lB + (wc * 64 + n * 16 + lr) * 64 + kk + lh * 8);
#pragma unroll
      for (int m = 0; m < 4; ++m)
#pragma unroll
        for (int n = 0; n < 4; ++n)
          acc[m][n] = __builtin_amdgcn_mfma_f32_16x16x32_bf16(av[m], bv[n], acc[m][n], 0, 0, 0);
    }
    __syncthreads();
  }
}

#define ACC_INIT(acc)                                   \
  _Pragma("unroll") for (int m_ = 0; m_ < 4; ++m_)      \
  _Pragma("unroll") for (int n_ = 0; n_ < 4; ++n_)      \
      acc[m_][n_] = (f32x4){0.f, 0.f, 0.f, 0.f};

// ---- KV^T partials: per (bh, chunk) C[e,d] = sum_t V[t,e]K[t,d] over 512 t --
__global__ __launch_bounds__(256) void kvt_partial_kernel(
    const unsigned short* __restrict__ VT, const unsigned short* __restrict__ KT,
    float* __restrict__ part) {
  __shared__ unsigned short lA[128 * 64], lB[128 * 64];
  const int z = blockIdx.x;            // 0..511 = bh*8 + chunk
  const int bh = z >> 3, c = z & 7;
  const int b = bh >> 4, h = bh & 15;
  const long tOff = (long)b * SEQ + (long)c * 512;
  const unsigned short* A  = VT + (long)(h * DKH) * M_TOK + tOff;
  const unsigned short* Bm = KT + (long)(h * DKH) * M_TOK + tOff;
  f32x4 acc[4][4];
  ACC_INIT(acc);
  gemm_mainloop(A, M_TOK, Bm, M_TOK, 512, lA, lB, acc);
  const int lane = threadIdx.x & 63, wid = threadIdx.x >> 6;
  const int wr = wid >> 1, wc = wid & 1, lr = lane & 15, lh = lane >> 4;
  float* out = part + (long)z * (DKH * DKH);
#pragma unroll
  for (int m = 0; m < 4; ++m)
#pragma unroll
    for (int n = 0; n < 4; ++n)
#pragma unroll
      for (int r = 0; r < 4; ++r) {
        int row = wr * 64 + m * 16 + lh * 4 + r;   // e
        int col = wc * 64 + n * 16 + lr;           // d
        out[row * DKH + col] = acc[m][n][r];
      }
}

__global__ __launch_bounds__(256) void reduce_kvt_kernel(
    const float* __restrict__ part, unsigned short* __restrict__ kvt) {
  int i = blockIdx.x * 256 + threadIdx.x;          // over 64*16384
  if (i < NBH * DKH * DKH) {
    int bh = i >> 14, j = i & 16383;
    float s = 0.f;
#pragma unroll
    for (int c = 0; c < 8; ++c) s += part[(((long)bh * 8 + c) << 14) + j];
    kvt[i] = f2bf(s);
  }
}

// ---- K row sums: Ksum[bh*128+d] = sum_t KT[(h*128+d)*M_TOK + b*4096 + t] ----
__global__ __launch_bounds__(256) void ksum_kernel(const unsigned short* __restrict__ KT,
                                                   float* __restrict__ ksum) {
  int gr = blockIdx.x * 4 + (threadIdx.x >> 6);    // 0..8191 = bh*128+d
  int lane = threadIdx.x & 63;
  int bh = gr >> 7, d = gr & 127;
  int b = bh >> 4, h = bh & 15;
  const unsigned short* p = KT + (long)(h * DKH + d) * M_TOK + (long)b * SEQ;
  float s = 0.f;
#pragma unroll
  for (int i = 0; i < 8; ++i) {
    uint4 v = *reinterpret_cast<const uint4*>(p + (i * 64 + lane) * 8);
    unsigned w[4] = {v.x, v.y, v.z, v.w};
#pragma unroll
    for (int j = 0; j < 4; ++j) {
      s += bf2f((unsigned short)(w[j] & 0xffff));
      s += bf2f((unsigned short)(w[j] >> 16));
    }
  }
#pragma unroll
  for (int o = 32; o > 0; o >>= 1) s += __shfl_down(s, o);
  if (lane == 0) ksum[gr] = s;
}

// ---- qsum[bh*4096+s] = sum_d Q[(b*4096+s)*2048 + h*128 + d] * Ksum[bh*128+d]
__global__ __launch_bounds__(256) void qsum_kernel(const unsigned short* __restrict__ Q,
                                                   const float* __restrict__ ksum,
                                                   float* __restrict__ qsum) {
  int gr = blockIdx.x * 4 + (threadIdx.x >> 6);    // 0..262143 = bh*4096 + s
  int lane = threadIdx.x & 63;
  int bh = gr >> 12, s = gr & 4095;
  int b = bh >> 4, h = bh & 15;
  const unsigned short* q = Q + ((long)b * SEQ + s) * D_MODEL + h * DKH + lane * 2;
  unsigned u = *reinterpret_cast<const unsigned*>(q);
  const float* ks = ksum + bh * DKH + lane * 2;
  float sum = bf2f((unsigned short)(u & 0xffff)) * ks[0] +
              bf2f((unsigned short)(u >> 16)) * ks[1];
#pragma unroll
  for (int o = 32; o > 0; o >>= 1) sum += __shfl_down(sum, o);
  if (lane == 0) qsum[gr] = sum;
}

// ---- QKV: per (bh), C[s,e] = sum_d Q[s,d]*KVT[e,d]; divide by qsum ---------
__global__ __launch_bounds__(256) void qkv_kernel(const unsigned short* __restrict__ Q,
                                                  const unsigned short* __restrict__ KVT,
                                                  const float* __restrict__ qsum,
                                                  unsigned short* __restrict__ attn) {
  __shared__ unsigned short lA[128 * 64], lB[128 * 64];
  const int z = blockIdx.z, b = z >> 4, h = z & 15;
  const long m0 = (long)blockIdx.y * 128;
  const unsigned short* A  = Q + ((long)b * SEQ + m0) * D_MODEL + h * DKH;
  const unsigned short* Bm = KVT + (long)z * (DKH * DKH);
  f32x4 acc[4][4];
  ACC_INIT(acc);
  gemm_mainloop(A, D_MODEL, Bm, DKH, DKH, lA, lB, acc);
  const int lane = threadIdx.x & 63, wid = threadIdx.x >> 6;
  const int wr = wid >> 1, wc = wid & 1, lr = lane & 15, lh = lane >> 4;
#pragma unroll
  for (int m = 0; m < 4; ++m)
#pragma unroll
    for (int n = 0; n < 4; ++n)
#pragma unroll
      for (int r = 0; r < 4; ++r) {
        long row = m0 + wr * 64 + m * 16 + lh * 4 + r;   // s in [0,4096)
        int  col = wc * 64 + n * 16 + lr;                // e in [0,128)
        float dnm = qsum[(long)z * SEQ + row] + 1e-8f;
        float v = acc[m][n][r] / dnm;
        attn[((long)b * SEQ + row) * D_MODEL + h * DKH + col] = f2bf(v);
      }
}

// ---- workspace layout (bytes) ----------------------------------------------
#define OFF_XB   0L
#define OFF_WQ   (OFF_XB + (long)M_TOK * D_MODEL * 2)
#define OFF_WK   (OFF_WQ + (long)D_MODEL * D_MODEL * 2)
#define OFF_WV   (OFF_WK + (long)D_MODEL * D_MODEL * 2)
#define OFF_WO   (OFF_WV + (long)D_MODEL * D_MODEL * 2)
#define OFF_QB   (OFF_WO + (long)D_MODEL * D_MODEL * 2)
#define OFF_KT   (OFF_QB + (long)M_TOK * D_MODEL * 2)
#define OFF_VT   (OFF_KT + (long)M_TOK * D_MODEL * 2)
#define OFF_PART (OFF_VT + (long)M_TOK * D_MODEL * 2)
#define OFF_KVT  (OFF_PART + (long)512 * DKH * DKH * 4)
#define OFF_KSUM (OFF_KVT + (long)NBH * DKH * DKH * 2)
#define OFF_QSUM (OFF_KSUM + (long)NBH * DKH * 4)
#define OFF_ATTN OFF_XB   // alias: x_bf16 dead after V^T projection

extern "C" void kernel_launch(void* const* d_in, const int* in_sizes, int n_in,
                              void* d_out, int out_size, void* d_ws, size_t ws_size,
                              hipStream_t stream) {
  const float* x  = (const float*)d_in[0];
  const float* wq = (const float*)d_in[1];
  const float* bq = (const float*)d_in[2];
  const float* wk = (const float*)d_in[3];
  const float* bk = (const float*)d_in[4];
  const float* wv = (const float*)d_in[5];
  const float* bv = (const float*)d_in[6];
  const float* wo = (const float*)d_in[7];
  const float* bo = (const float*)d_in[8];

  char* ws = (char*)d_ws;
  unsigned short* xb   = (unsigned short*)(ws + OFF_XB);
  unsigned short* wqb  = (unsigned short*)(ws + OFF_WQ);
  unsigned short* wkb  = (unsigned short*)(ws + OFF_WK);
  unsigned short* wvb  = (unsigned short*)(ws + OFF_WV);
  unsigned short* wob  = (unsigned short*)(ws + OFF_WO);
  unsigned short* Qb   = (unsigned short*)(ws + OFF_QB);
  unsigned short* KTb  = (unsigned short*)(ws + OFF_KT);
  unsigned short* VTb  = (unsigned short*)(ws + OFF_VT);
  float*          part = (float*)(ws + OFF_PART);
  unsigned short* KVTb = (unsigned short*)(ws + OFF_KVT);
  float*          ksum = (float*)(ws + OFF_KSUM);
  float*          qsum = (float*)(ws + OFF_QSUM);
  unsigned short* attn = (unsigned short*)(ws + OFF_ATTN);

  dim3 blk(256);
  dim3 blk5(512);

  // fp32 -> bf16
  convert_f2bf_kernel<<<(M_TOK * D_MODEL / 4) / 256, blk, 0, stream>>>(x, xb, M_TOK * D_MODEL / 4);
  convert_f2bf_kernel<<<(D_MODEL * D_MODEL / 4) / 256, blk, 0, stream>>>(wq, wqb, D_MODEL * D_MODEL / 4);
  convert_f2bf_kernel<<<(D_MODEL * D_MODEL / 4) / 256, blk, 0, stream>>>(wk, wkb, D_MODEL * D_MODEL / 4);
  convert_f2bf_kernel<<<(D_MODEL * D_MODEL / 4) / 256, blk, 0, stream>>>(wv, wvb, D_MODEL * D_MODEL / 4);
  convert_f2bf_kernel<<<(D_MODEL * D_MODEL / 4) / 256, blk, 0, stream>>>(wo, wob, D_MODEL * D_MODEL / 4);

  // Q = elu(x@Wq^T + bq)+1                       (M_TOK x 2048)
  gemm256_nt_kernel<0><<<dim3(D_MODEL / 256, M_TOK / 256), blk5, 0, stream>>>(
      xb, D_MODEL, wqb, D_MODEL, Qb, D_MODEL, bq, D_MODEL);
  // K^T = elu(Wk@x^T + bk)+1  (2048 x M_TOK), V^T = Wv@x^T + bv
  gemm256_nt_kernel<1><<<dim3(M_TOK / 256, D_MODEL / 256), blk5, 0, stream>>>(
      wkb, D_MODEL, xb, D_MODEL, KTb, M_TOK, bk, D_MODEL);
  gemm256_nt_kernel<2><<<dim3(M_TOK / 256, D_MODEL / 256), blk5, 0, stream>>>(
      wvb, D_MODEL, xb, D_MODEL, VTb, M_TOK, bv, D_MODEL);

  // KV^T per (b,h) via split-K partials + reduce
  kvt_partial_kernel<<<512, blk, 0, stream>>>(VTb, KTb, part);
  reduce_kvt_kernel<<<(NBH * DKH * DKH) / 256, blk, 0, stream>>>(part, KVTb);

  // K_sum and per-row denominators
  ksum_kernel<<<(NBH * DKH) / 4, blk, 0, stream>>>(KTb, ksum);
  qsum_kernel<<<(NBH * SEQ) / 4, blk, 0, stream>>>(Qb, ksum, qsum);

  // attn = (Q @ KV) / (Q . Ksum + 1e-8)   -> bf16 (aliases xb)
  qkv_kernel<<<dim3(1, SEQ / 128, NBH), blk, 0, stream>>>(Qb, KVTb, qsum, attn);

  // out = attn @ Wo^T + bo  -> fp32
  gemm256_nt_kernel<3><<<dim3(D_MODEL / 256, M_TOK / 256), blk5, 0, stream>>>(
      attn, D_MODEL, wob, D_MODEL, d_out, D_MODEL, bo, D_MODEL);
}

// Round 4
// 690.268 us; speedup vs baseline: 1.5048x; 1.1662x over previous
//
#include <hip/hip_runtime.h>

// Linear attention (elu+1 feature map), B=4 S=4096 D=2048 H=16 dk=128.
// bf16 MFMA, fp32 accumulate.
// Round 4: m201-geometry 256x256 GEMM — BK=64, 128 KiB LDS dbuf, 4 phases x
// 16 MFMA per K-tile, counted vmcnt(8) (never 0 in steady state), T2 XOR
// swizzle (source-side pre-swizzle), T5 setprio, T1 bijective XCD swizzle.

#define D_MODEL 2048
#define SEQ     4096
#define BATCH   4
#define HEADS   16
#define DKH     128
#define M_TOK   16384   // BATCH*SEQ
#define NBH     64      // BATCH*HEADS

using frag8 = __attribute__((ext_vector_type(8))) short;   // 8 bf16 (4 VGPRs)
using f32x4 = __attribute__((ext_vector_type(4))) float;   // 4 fp32 acc

typedef __attribute__((address_space(1))) const unsigned int g_u32;
typedef __attribute__((address_space(3))) unsigned int       l_u32;

__device__ __forceinline__ unsigned short f2bf(float f) {
  unsigned u = __float_as_uint(f);
  u = u + 0x7fffu + ((u >> 16) & 1u);   // round-to-nearest-even
  return (unsigned short)(u >> 16);
}
__device__ __forceinline__ float bf2f(unsigned short h) {
  return __uint_as_float(((unsigned)h) << 16);
}

// ---- fp32 -> bf16 convert (vectorized) --------------------------------------
__global__ __launch_bounds__(256) void convert_f2bf_kernel(
    const float* __restrict__ in, unsigned short* __restrict__ out, int n4) {
  int i = blockIdx.x * 256 + threadIdx.x;
  if (i < n4) {
    float4 v = reinterpret_cast<const float4*>(in)[i];
    ushort4 o;
    o.x = f2bf(v.x); o.y = f2bf(v.y); o.z = f2bf(v.z); o.w = f2bf(v.w);
    reinterpret_cast<ushort4*>(out)[i] = o;
  }
}

// ============================================================================
// 256x256x(BK=64) phased GEMM, C = A(256xK) * B(256xK)^T, bf16 NT.
// 512 thr = 8 waves (2M x 4N); per-wave C = 128x64 = 8m x 4n frags.
// LDS 128 KiB: buf[p] = { A 256x64, B 256x64 } bf16, p in {0,1}.
// Swizzle: LDS byte col c' = c ^ ((row&7)<<4); inverse applied to global src.
// ============================================================================

// Stage one full K-tile (A 32 KB + B 32 KB) = 8 global_load_lds per thread.
__device__ __forceinline__ void stage_tile64(const unsigned short* __restrict__ GA, long lda,
                                             const unsigned short* __restrict__ GB, long ldb,
                                             unsigned short* __restrict__ L,
                                             int wid, int lane) {
  const int rsub = lane >> 3;                    // row within 8-row group
  const int ge   = ((lane & 7) ^ rsub) * 8;      // pre-swizzled col (elems)
#pragma unroll
  for (int r = 0; r < 4; ++r) {
    const int row = r * 64 + wid * 8 + rsub;
    __builtin_amdgcn_global_load_lds((g_u32*)(GA + (long)row * lda + ge),
                                     (l_u32*)(L + r * 4096 + wid * 512), 16, 0, 0);
  }
#pragma unroll
  for (int r = 0; r < 4; ++r) {
    const int row = r * 64 + wid * 8 + rsub;
    __builtin_amdgcn_global_load_lds((g_u32*)(GB + (long)row * ldb + ge),
                                     (l_u32*)(L + 16384 + r * 4096 + wid * 512), 16, 0, 0);
  }
}

#define DS_AV(MS, KK)                                                         \
  _Pragma("unroll") for (int i_ = 0; i_ < 4; ++i_) {                          \
    const int row_ = wm * 128 + (MS) * 64 + i_ * 16 + lr;                     \
    const int cb_ = (((KK) * 2 + lh * 16) ^ ((lr & 7) << 4)) >> 1;            \
    av[i_] = *(const frag8*)(lA + row_ * 64 + cb_);                           \
  }
#define DS_BV(KK)                                                             \
  _Pragma("unroll") for (int n_ = 0; n_ < 4; ++n_) {                          \
    const int row_ = wn * 64 + n_ * 16 + lr;                                  \
    const int cb_ = (((KK) * 2 + lh * 16) ^ ((lr & 7) << 4)) >> 1;            \
    bv[n_] = *(const frag8*)(lB + row_ * 64 + cb_);                           \
  }
#define MFMA16(MS)                                                            \
  __builtin_amdgcn_s_setprio(1);                                              \
  _Pragma("unroll") for (int i_ = 0; i_ < 4; ++i_)                            \
  _Pragma("unroll") for (int n_ = 0; n_ < 4; ++n_)                            \
    acc[(MS) * 4 + i_][n_] = __builtin_amdgcn_mfma_f32_16x16x32_bf16(         \
        av[i_], bv[n_], acc[(MS) * 4 + i_][n_], 0, 0, 0);                     \
  __builtin_amdgcn_s_setprio(0);
#define LGKM0                                                                 \
  asm volatile("s_waitcnt lgkmcnt(0)" ::: "memory");                          \
  __builtin_amdgcn_sched_barrier(0)

// MODE: 0 = elu(v+bias[col])+1 -> bf16   (Q projection)
//       1 = elu(v+bias[row])+1 -> bf16   (K^T projection)
//       2 = v+bias[row]        -> bf16   (V^T projection)
//       3 = v+bias[col]        -> f32    (final output projection)
template <int MODE, bool XMAJOR>
__global__ __launch_bounds__(512, 2) void gemm256_nt_kernel(
    const unsigned short* __restrict__ A, long lda,
    const unsigned short* __restrict__ Bm, long ldb,
    void* __restrict__ Cv, long ldc,
    const float* __restrict__ bias, int K) {
  __shared__ unsigned short sh[65536];   // 128 KiB
  const int lane = threadIdx.x & 63, wid = threadIdx.x >> 6;
  const int wm = wid >> 2, wn = wid & 3;
  const int lr = lane & 15, lh = lane >> 4;

  // T1 bijective XCD swizzle; per-XCD chunk covers an ~8x8 block sub-grid.
  const int gx = gridDim.x, gy = gridDim.y;
  const int cpx = (gx * gy) >> 3;
  const int P = blockIdx.y * gx + blockIdx.x;
  const int L = (P & 7) * cpx + (P >> 3);
  int bx, by;
  if (XMAJOR) { bx = L / gy; by = L - bx * gy; }
  else        { by = L / gx; bx = L - by * gx; }

  const long m0 = (long)by * 256, n0 = (long)bx * 256;
  const unsigned short* Ablk = A + m0 * lda;
  const unsigned short* Bblk = Bm + n0 * ldb;
  const int NT = K >> 6;

  f32x4 acc[8][4];
#pragma unroll
  for (int m = 0; m < 8; ++m)
#pragma unroll
    for (int n = 0; n < 4; ++n) acc[m][n] = (f32x4){0.f, 0.f, 0.f, 0.f};

  // prologue: tiles 0 -> buf0, 1 -> buf1
  stage_tile64(Ablk, lda, Bblk, ldb, sh, wid, lane);
  if (NT > 1)
    stage_tile64(Ablk + 64, lda, Bblk + 64, ldb, sh + 32768, wid, lane);

  for (int t = 0; t < NT; ++t) {
    const unsigned short* lA = sh + (t & 1) * 32768;
    const unsigned short* lB = lA + 16384;
    // stage tile t+1 into the buffer freed at end of tile t-1
    if (t >= 1 && t + 1 < NT)
      stage_tile64(Ablk + (long)(t + 1) * 64, lda, Bblk + (long)(t + 1) * 64, ldb,
                   (unsigned short*)sh + ((t + 1) & 1) * 32768, wid, lane);
    if (t + 1 < NT) asm volatile("s_waitcnt vmcnt(8)" ::: "memory");
    else            asm volatile("s_waitcnt vmcnt(0)" ::: "memory");
    __builtin_amdgcn_s_barrier();           // tile t fully in LDS for all waves
    frag8 av[4], bv[4];
    // ph0: m-half 0, kk=0 (+ bv kk0)
    DS_AV(0, 0); DS_BV(0);
    LGKM0; MFMA16(0);
    // ph1: m-half 1, kk=0 (reads hoisted before barrier)
    DS_AV(1, 0);
    __builtin_amdgcn_s_barrier();
    LGKM0; MFMA16(1);
    // ph2: m-half 0, kk=32
    DS_AV(0, 32); DS_BV(32);
    __builtin_amdgcn_s_barrier();
    LGKM0; MFMA16(0);
    // ph3: m-half 1, kk=32
    DS_AV(1, 32);
    __builtin_amdgcn_s_barrier();
    LGKM0; MFMA16(1);
    __builtin_amdgcn_s_barrier();           // all reads of buf[t&1] done
  }

  // epilogue: frag m covers rows (m>>2)*64 + (m&3)*16 of the wave's 128
#pragma unroll
  for (int m = 0; m < 8; ++m)
#pragma unroll
    for (int n = 0; n < 4; ++n)
#pragma unroll
      for (int r = 0; r < 4; ++r) {
        long row = m0 + wm * 128 + (m >> 2) * 64 + (m & 3) * 16 + lh * 4 + r;
        long col = n0 + wn * 64 + n * 16 + lr;
        float v = acc[m][n][r];
        if (MODE == 0) {
          v += bias[col]; v = v > 0.f ? v + 1.f : __expf(v);
          ((unsigned short*)Cv)[row * ldc + col] = f2bf(v);
        } else if (MODE == 1) {
          v += bias[row]; v = v > 0.f ? v + 1.f : __expf(v);
          ((unsigned short*)Cv)[row * ldc + col] = f2bf(v);
        } else if (MODE == 2) {
          v += bias[row];
          ((unsigned short*)Cv)[row * ldc + col] = f2bf(v);
        } else {
          v += bias[col];
          ((float*)Cv)[row * ldc + col] = v;
        }
      }
}

// ============================================================================
// 128x128 path (attention core) — unchanged.
// ============================================================================
__device__ __forceinline__ void stage_tile(const unsigned short* __restrict__ G,
                                           long ld, unsigned short* __restrict__ L) {
  const int w = threadIdx.x >> 6, l = threadIdx.x & 63;
#pragma unroll
  for (int r = 0; r < 4; ++r) {
    const int chunk = w * 4 + r;
    const int row = chunk * 8 + (l >> 3);
    const int col = (l & 7) * 8;
    __builtin_amdgcn_global_load_lds((g_u32*)(G + (long)row * ld + col),
                                     (l_u32*)(L + chunk * 512), 16, 0, 0);
  }
}

__device__ __forceinline__ void gemm_mainloop(const unsigned short* __restrict__ A, long lda,
                                              const unsigned short* __restrict__ B, long ldb,
                                              int K, unsigned short* lA, unsigned short* lB,
                                              f32x4 acc[4][4]) {
  const int lane = threadIdx.x & 63;
  const int wid  = threadIdx.x >> 6;
  const int wr = wid >> 1, wc = wid & 1;
  const int lr = lane & 15, lh = lane >> 4;
  for (int k0 = 0; k0 < K; k0 += 64) {
    stage_tile(A + k0, lda, lA);
    stage_tile(B + k0, ldb, lB);
    __syncthreads();
#pragma unroll
    for (int kk = 0; kk < 64; kk += 32) {
      frag8 av[4], bv[4];
#pragma unroll
      for (int m = 0; m < 4; ++m)
        av[m] = *reinterpret_cast<const frag8*>(lA + (wr * 64 + m * 16 + lr) * 64 + kk + lh * 8);
#pragma unroll
      for (int n = 0; n < 4; ++n)
        bv[n] = *reinterpret_cast<const frag8*>(lB + (wc * 64 + n * 16 + lr) * 64 + kk + lh * 8);
#pragma unroll
      for (int m = 0; m < 4; ++m)
#pragma unroll
        for (int n = 0; n < 4; ++n)
          acc[m][n] = __builtin_amdgcn_mfma_f32_16x16x32_bf16(av[m], bv[n], acc[m][n], 0, 0, 0);
    }
    __syncthreads();
  }
}

#define ACC_INIT(acc)                                   \
  _Pragma("unroll") for (int m_ = 0; m_ < 4; ++m_)      \
  _Pragma("unroll") for (int n_ = 0; n_ < 4; ++n_)      \
      acc[m_][n_] = (f32x4){0.f, 0.f, 0.f, 0.f};

// ---- KV^T partials: per (bh, chunk) C[e,d] = sum_t V[t,e]K[t,d] over 512 t --
__global__ __launch_bounds__(256) void kvt_partial_kernel(
    const unsigned short* __restrict__ VT, const unsigned short* __restrict__ KT,
    float* __restrict__ part) {
  __shared__ unsigned short lA[128 * 64], lB[128 * 64];
  const int z = blockIdx.x;            // 0..511 = bh*8 + chunk
  const int bh = z >> 3, c = z & 7;
  const int b = bh >> 4, h = bh & 15;
  const long tOff = (long)b * SEQ + (long)c * 512;
  const unsigned short* A  = VT + (long)(h * DKH) * M_TOK + tOff;
  const unsigned short* Bm = KT + (long)(h * DKH) * M_TOK + tOff;
  f32x4 acc[4][4];
  ACC_INIT(acc);
  gemm_mainloop(A, M_TOK, Bm, M_TOK, 512, lA, lB, acc);
  const int lane = threadIdx.x & 63, wid = threadIdx.x >> 6;
  const int wr = wid >> 1, wc = wid & 1, lr = lane & 15, lh = lane >> 4;
  float* out = part + (long)z * (DKH * DKH);
#pragma unroll
  for (int m = 0; m < 4; ++m)
#pragma unroll
    for (int n = 0; n < 4; ++n)
#pragma unroll
      for (int r = 0; r < 4; ++r) {
        int row = wr * 64 + m * 16 + lh * 4 + r;   // e
        int col = wc * 64 + n * 16 + lr;           // d
        out[row * DKH + col] = acc[m][n][r];
      }
}

__global__ __launch_bounds__(256) void reduce_kvt_kernel(
    const float* __restrict__ part, unsigned short* __restrict__ kvt) {
  int i = blockIdx.x * 256 + threadIdx.x;          // over 64*16384
  if (i < NBH * DKH * DKH) {
    int bh = i >> 14, j = i & 16383;
    float s = 0.f;
#pragma unroll
    for (int c = 0; c < 8; ++c) s += part[(((long)bh * 8 + c) << 14) + j];
    kvt[i] = f2bf(s);
  }
}

// ---- K row sums ------------------------------------------------------------
__global__ __launch_bounds__(256) void ksum_kernel(const unsigned short* __restrict__ KT,
                                                   float* __restrict__ ksum) {
  int gr = blockIdx.x * 4 + (threadIdx.x >> 6);    // 0..8191 = bh*128+d
  int lane = threadIdx.x & 63;
  int bh = gr >> 7, d = gr & 127;
  int b = bh >> 4, h = bh & 15;
  const unsigned short* p = KT + (long)(h * DKH + d) * M_TOK + (long)b * SEQ;
  float s = 0.f;
#pragma unroll
  for (int i = 0; i < 8; ++i) {
    uint4 v = *reinterpret_cast<const uint4*>(p + (i * 64 + lane) * 8);
    unsigned w[4] = {v.x, v.y, v.z, v.w};
#pragma unroll
    for (int j = 0; j < 4; ++j) {
      s += bf2f((unsigned short)(w[j] & 0xffff));
      s += bf2f((unsigned short)(w[j] >> 16));
    }
  }
#pragma unroll
  for (int o = 32; o > 0; o >>= 1) s += __shfl_down(s, o);
  if (lane == 0) ksum[gr] = s;
}

// ---- qsum ------------------------------------------------------------------
__global__ __launch_bounds__(256) void qsum_kernel(const unsigned short* __restrict__ Q,
                                                   const float* __restrict__ ksum,
                                                   float* __restrict__ qsum) {
  int gr = blockIdx.x * 4 + (threadIdx.x >> 6);    // 0..262143 = bh*4096 + s
  int lane = threadIdx.x & 63;
  int bh = gr >> 12, s = gr & 4095;
  int b = bh >> 4, h = bh & 15;
  const unsigned short* q = Q + ((long)b * SEQ + s) * D_MODEL + h * DKH + lane * 2;
  unsigned u = *reinterpret_cast<const unsigned*>(q);
  const float* ks = ksum + bh * DKH + lane * 2;
  float sum = bf2f((unsigned short)(u & 0xffff)) * ks[0] +
              bf2f((unsigned short)(u >> 16)) * ks[1];
#pragma unroll
  for (int o = 32; o > 0; o >>= 1) sum += __shfl_down(sum, o);
  if (lane == 0) qsum[gr] = sum;
}

// ---- QKV -------------------------------------------------------------------
__global__ __launch_bounds__(256) void qkv_kernel(const unsigned short* __restrict__ Q,
                                                  const unsigned short* __restrict__ KVT,
                                                  const float* __restrict__ qsum,
                                                  unsigned short* __restrict__ attn) {
  __shared__ unsigned short lA[128 * 64], lB[128 * 64];
  const int z = blockIdx.z, b = z >> 4, h = z & 15;
  const long m0 = (long)blockIdx.y * 128;
  const unsigned short* A  = Q + ((long)b * SEQ + m0) * D_MODEL + h * DKH;
  const unsigned short* Bm = KVT + (long)z * (DKH * DKH);
  f32x4 acc[4][4];
  ACC_INIT(acc);
  gemm_mainloop(A, D_MODEL, Bm, DKH, DKH, lA, lB, acc);
  const int lane = threadIdx.x & 63, wid = threadIdx.x >> 6;
  const int wr = wid >> 1, wc = wid & 1, lr = lane & 15, lh = lane >> 4;
#pragma unroll
  for (int m = 0; m < 4; ++m)
#pragma unroll
    for (int n = 0; n < 4; ++n)
#pragma unroll
      for (int r = 0; r < 4; ++r) {
        long row = m0 + wr * 64 + m * 16 + lh * 4 + r;   // s in [0,4096)
        int  col = wc * 64 + n * 16 + lr;                // e in [0,128)
        float dnm = qsum[(long)z * SEQ + row] + 1e-8f;
        float v = acc[m][n][r] / dnm;
        attn[((long)b * SEQ + row) * D_MODEL + h * DKH + col] = f2bf(v);
      }
}

// ---- workspace layout (bytes) ----------------------------------------------
#define OFF_XB   0L
#define OFF_WQ   (OFF_XB + (long)M_TOK * D_MODEL * 2)
#define OFF_WK   (OFF_WQ + (long)D_MODEL * D_MODEL * 2)
#define OFF_WV   (OFF_WK + (long)D_MODEL * D_MODEL * 2)
#define OFF_WO   (OFF_WV + (long)D_MODEL * D_MODEL * 2)
#define OFF_QB   (OFF_WO + (long)D_MODEL * D_MODEL * 2)
#define OFF_KT   (OFF_QB + (long)M_TOK * D_MODEL * 2)
#define OFF_VT   (OFF_KT + (long)M_TOK * D_MODEL * 2)
#define OFF_PART (OFF_VT + (long)M_TOK * D_MODEL * 2)
#define OFF_KVT  (OFF_PART + (long)512 * DKH * DKH * 4)
#define OFF_KSUM (OFF_KVT + (long)NBH * DKH * DKH * 2)
#define OFF_QSUM (OFF_KSUM + (long)NBH * DKH * 4)
#define OFF_ATTN OFF_XB   // alias: x_bf16 dead after V^T projection

extern "C" void kernel_launch(void* const* d_in, const int* in_sizes, int n_in,
                              void* d_out, int out_size, void* d_ws, size_t ws_size,
                              hipStream_t stream) {
  const float* x  = (const float*)d_in[0];
  const float* wq = (const float*)d_in[1];
  const float* bq = (const float*)d_in[2];
  const float* wk = (const float*)d_in[3];
  const float* bk = (const float*)d_in[4];
  const float* wv = (const float*)d_in[5];
  const float* bv = (const float*)d_in[6];
  const float* wo = (const float*)d_in[7];
  const float* bo = (const float*)d_in[8];

  char* ws = (char*)d_ws;
  unsigned short* xb   = (unsigned short*)(ws + OFF_XB);
  unsigned short* wqb  = (unsigned short*)(ws + OFF_WQ);
  unsigned short* wkb  = (unsigned short*)(ws + OFF_WK);
  unsigned short* wvb  = (unsigned short*)(ws + OFF_WV);
  unsigned short* wob  = (unsigned short*)(ws + OFF_WO);
  unsigned short* Qb   = (unsigned short*)(ws + OFF_QB);
  unsigned short* KTb  = (unsigned short*)(ws + OFF_KT);
  unsigned short* VTb  = (unsigned short*)(ws + OFF_VT);
  float*          part = (float*)(ws + OFF_PART);
  unsigned short* KVTb = (unsigned short*)(ws + OFF_KVT);
  float*          ksum = (float*)(ws + OFF_KSUM);
  float*          qsum = (float*)(ws + OFF_QSUM);
  unsigned short* attn = (unsigned short*)(ws + OFF_ATTN);

  dim3 blk(256);
  dim3 blk5(512);

  // fp32 -> bf16
  convert_f2bf_kernel<<<(M_TOK * D_MODEL / 4) / 256, blk, 0, stream>>>(x, xb, M_TOK * D_MODEL / 4);
  convert_f2bf_kernel<<<(D_MODEL * D_MODEL / 4) / 256, blk, 0, stream>>>(wq, wqb, D_MODEL * D_MODEL / 4);
  convert_f2bf_kernel<<<(D_MODEL * D_MODEL / 4) / 256, blk, 0, stream>>>(wk, wkb, D_MODEL * D_MODEL / 4);
  convert_f2bf_kernel<<<(D_MODEL * D_MODEL / 4) / 256, blk, 0, stream>>>(wv, wvb, D_MODEL * D_MODEL / 4);
  convert_f2bf_kernel<<<(D_MODEL * D_MODEL / 4) / 256, blk, 0, stream>>>(wo, wob, D_MODEL * D_MODEL / 4);

  // Q = elu(x@Wq^T + bq)+1                       (M_TOK x 2048)
  gemm256_nt_kernel<0, false><<<dim3(D_MODEL / 256, M_TOK / 256), blk5, 0, stream>>>(
      xb, D_MODEL, wqb, D_MODEL, Qb, D_MODEL, bq, D_MODEL);
  // K^T = elu(Wk@x^T + bk)+1  (2048 x M_TOK), V^T = Wv@x^T + bv
  gemm256_nt_kernel<1, true><<<dim3(M_TOK / 256, D_MODEL / 256), blk5, 0, stream>>>(
      wkb, D_MODEL, xb, D_MODEL, KTb, M_TOK, bk, D_MODEL);
  gemm256_nt_kernel<2, true><<<dim3(M_TOK / 256, D_MODEL / 256), blk5, 0, stream>>>(
      wvb, D_MODEL, xb, D_MODEL, VTb, M_TOK, bv, D_MODEL);

  // KV^T per (b,h) via split-K partials + reduce
  kvt_partial_kernel<<<512, blk, 0, stream>>>(VTb, KTb, part);
  reduce_kvt_kernel<<<(NBH * DKH * DKH) / 256, blk, 0, stream>>>(part, KVTb);

  // K_sum and per-row denominators
  ksum_kernel<<<(NBH * DKH) / 4, blk, 0, stream>>>(KTb, ksum);
  qsum_kernel<<<(NBH * SEQ) / 4, blk, 0, stream>>>(Qb, ksum, qsum);

  // attn = (Q @ KV) / (Q . Ksum + 1e-8)   -> bf16 (aliases xb)
  qkv_kernel<<<dim3(1, SEQ / 128, NBH), blk, 0, stream>>>(Qb, KVTb, qsum, attn);

  // out = attn @ Wo^T + bo  -> fp32
  gemm256_nt_kernel<3, false><<<dim3(D_MODEL / 256, M_TOK / 256), blk5, 0, stream>>>(
      attn, D_MODEL, wob, D_MODEL, d_out, D_MODEL, bo, D_MODEL);
}